// Round 7
// baseline (2278.158 us; speedup 1.0000x reference)
//
#include <hip/hip_runtime.h>
#include <math.h>

// Problem constants: T=512, B=64, I=256, H=1024, O=256
// d_out layout: outputs [512*64][256] fp32, then hidden_states [512*64][1024] fp32.

typedef __attribute__((ext_vector_type(8))) short s16x8;
typedef __attribute__((ext_vector_type(4))) short s16x4;
typedef __attribute__((ext_vector_type(4))) float f32x4;
typedef unsigned long long u64;

__device__ __forceinline__ short f2bf(float f) {
  union { float f; unsigned u; } v; v.f = f;
  unsigned r = v.u + 0x7FFFu + ((v.u >> 16) & 1u);  // RNE
  return (short)(r >> 16);
}

__device__ __forceinline__ f32x4 mfma16(s16x8 a, s16x8 b, f32x4 c) {
  return __builtin_amdgcn_mfma_f32_16x16x32_bf16(a, b, c, 0, 0, 0);
}

// tanh via v_exp_f32: t = 1 - 2/(e^{2x}+1). Monotone-safe at +-inf, no NaN.
__device__ __forceinline__ float fast_tanh(float x) {
  float e = __expf(2.0f * x);
  return 1.0f - 2.0f * __builtin_amdgcn_rcpf(e + 1.0f);
}

// ---------------- converters / init ----------------

__global__ void cvt_bf16x4(const float* __restrict__ in, short* __restrict__ out, int n4) {
  int i = blockIdx.x * 256 + threadIdx.x;
  if (i < n4) {
    const float4 v = ((const float4*)in)[i];
    s16x4 o = { f2bf(v.x), f2bf(v.y), f2bf(v.z), f2bf(v.w) };
    ((s16x4*)out)[i] = o;
  }
}

// staging32: [2 slots][64 rows][1024] tagged dwords: (bf16 << 16) | step_tag.
// slot1 = h_{-1} = broadcast h0, tag 0 (consumer at t=0 expects tag 0).
// slot0 zeroed: tag 0 never matches its first expected tag (odd t >= 1).
__global__ void init_staging32(const float* __restrict__ h0, unsigned* __restrict__ staging) {
  int i = blockIdx.x * 256 + threadIdx.x;  // 2*64*1024 = 131072
  if (i < 131072) {
    int slot = i >> 16;
    int k = i & 1023;
    staging[i] = slot ? (((unsigned)(unsigned short)f2bf(h0[k])) << 16) : 0u;
  }
}

// ---------------- generic NT GEMM: out[M][N] = A[M][K](bf16) * B[N][K](bf16)^T + bias ----------------

template <int K>
__global__ __launch_bounds__(256) void gemm_nt_bias(
    const short* __restrict__ A, const short* __restrict__ B,
    const float* __restrict__ bias, float* __restrict__ out, int N) {
  const int tid = threadIdx.x;
  const int lane = tid & 63, wv = tid >> 6;
  const int m0 = blockIdx.x * 64 + (wv & 1) * 32;
  const int n0 = blockIdx.y * 64 + (wv >> 1) * 32;
  const int lm = lane & 15, q = lane >> 4;

  const short* a0p = A + (m0 + lm) * K + q * 8;
  const short* a1p = a0p + 16 * K;
  const short* b0p = B + (n0 + lm) * K + q * 8;
  const short* b1p = b0p + 16 * K;

  f32x4 c00 = {0.f,0.f,0.f,0.f}, c01 = {0.f,0.f,0.f,0.f};
  f32x4 c10 = {0.f,0.f,0.f,0.f}, c11 = {0.f,0.f,0.f,0.f};

#pragma unroll
  for (int kk = 0; kk < K; kk += 32) {
    s16x8 a0 = *(const s16x8*)(a0p + kk);
    s16x8 a1 = *(const s16x8*)(a1p + kk);
    s16x8 b0 = *(const s16x8*)(b0p + kk);
    s16x8 b1 = *(const s16x8*)(b1p + kk);
    c00 = mfma16(a0, b0, c00);
    c01 = mfma16(a0, b1, c01);
    c10 = mfma16(a1, b0, c10);
    c11 = mfma16(a1, b1, c11);
  }

  const int col0 = n0 + lm;
  const float bi0 = bias[col0], bi1 = bias[col0 + 16];
#pragma unroll
  for (int r = 0; r < 4; ++r) {
    int row = m0 + q * 4 + r;
    out[row * N + col0]        = c00[r] + bi0;
    out[row * N + col0 + 16]   = c01[r] + bi1;
    out[(row + 16) * N + col0]      = c10[r] + bi0;
    out[(row + 16) * N + col0 + 16] = c11[r] + bi1;
  }
}

// ---------------- recurrent kernel ----------------
// R7: R6's 64-WG/256-thread structure + R4's tag-in-data protocol at the
// coalesced granularity, + conflict-free LDS staging writes.
//
// group g = bid&7 owns batch rows [8g,8g+8); WG w = bid>>3 owns hidden cols
// [128w,128w+128); wave v owns cols [128w+32v,+32) with the verified
// bf[32][2] wR register layout and MFMA fragments.
//
// Protocol: staging32 words = (bf16 << 16) | step_tag. Producer at step t
// writes slot t&1 with tag t+1 (relaxed system 8B stores) and PROCEEDS —
// no vmcnt ack, no barrier, no flag. Consumer at step t cooperatively loads
// slot (t+1)&1 (per wave: 4 rounds x 2KB contiguous, lane-interleaved 32B)
// expecting tag t; value+tag share one single-copy-atomic dword, so tag==t
// proves the value is step-t's — the load IS the poll; stale rounds retry.
// Overwrite safety (same induction as R4, WG granularity): a peer reaches
// its step t+1 stores into slot (t+1)&1 only after consuming OUR h_t chunk
// (tag t+1), which we publish only after our step-t reads of slot (t+1)&1
// completed (stores are data-dependent on the full tile via MFMA). So no
// tag t+2 can appear in slot (t+1)&1 while we still read it. Cross-launch
// staleness impossible: init rewrites both slots; system-scope loads bypass
// L1/L2. Own chunk validates like any other (own stores visible to self).
//
// LDS: tile double-buffered (2 x 16KB) -> ONE __syncthreads per step (between
// tile write and tile read); a wave ahead writes buf (t+1)&1 while a slow
// wave reads buf t&1. lh repack is wave-private (no barrier). Staging writes
// to LDS are lane-contiguous ds_write_b128 (R6's 64B-per-thread chunks were
// a 16-way bank conflict: all lanes differed only in addr bit 6 -> 3.0e7
// SQ_LDS_BANK_CONFLICT). XOR swizzle (byte ^ row<<6) unchanged from R6
// (numerically verified there); all lanes of one write share a row, so the
// XOR is a constant position permutation -> still conflict-free.

__global__ __launch_bounds__(256, 1) void rnn_recur(
    const float* __restrict__ wR,     // [1024][1024] fp32, k-major
    float* __restrict__ hid,          // [512*64][1024] fp32: xp on entry, h on exit
    short* __restrict__ hs_bf,        // [512*64][1024] bf16 copy of h (for phase C)
    unsigned* __restrict__ staging)   // [2][64][1024] tagged dwords
{
  __shared__ short tile2[2][8 * 1024];  // 2 x 16KB packed h tiles (8 x 1024 bf16)
  __shared__ short lh[4 * 256];         // per-wave 8x32 repack buffers (4 x 512B)

  const int tid = threadIdx.x;
  const int lane = tid & 63;
  const int v = tid >> 6;             // wave 0..3
  const int g = blockIdx.x & 7;
  const int w = blockIdx.x >> 3;      // 0..7
  const int m = lane & 15, q = lane >> 4;
  const int rowbase = g * 8;
  const int colbase = w * 128 + v * 32;

  // --- one-time: pack wR[:, colbase..colbase+32) into B-fragments in registers ---
  s16x8 bf[32][2];
#pragma unroll
  for (int cc = 0; cc < 32; ++cc) {
#pragma unroll
    for (int tn = 0; tn < 2; ++tn) {
      const int kb = cc * 32 + q * 8;
      const int n = colbase + tn * 16 + m;
      s16x8 vv;
#pragma unroll
      for (int j = 0; j < 8; ++j) vv[j] = f2bf(wR[(kb + j) * 1024 + n]);
      bf[cc][tn] = vv;
    }
  }

  const int gr = rowbase + q * 4;     // epilogue rows (valid when q<2)
  const int lr = q * 4;               // local row base in lh
  const int prow = lane >> 3;         // packed-store row: lane i>>3, 4 cols (i&7)*4
  short* lhv = lh + v * 256;

  // MFMA-read swizzle (verified in R6): byte = arow*2048 + ((cc*64+q*16)^axor)
  const int arow = m & 7;
  const int axor = arow << 6;

  const u64 TAGMASK = 0x0000FFFF0000FFFFull;
  const int chbase = v * 4;           // this wave's 4 load-chunks (of 16)

#pragma unroll 1
  for (int t = 0; t < 512; ++t) {
    const int tb = t * 64;

    // prefetch xp (independent of the protocol) to hide HBM latency
    float xp0[4] = {0.f,0.f,0.f,0.f}, xp1[4] = {0.f,0.f,0.f,0.f};
    if (q < 2) {
#pragma unroll
      for (int r = 0; r < 4; ++r) {
        int ro = (tb + gr + r) * 1024;
        xp0[r] = hid[ro + colbase + m];
        xp1[r] = hid[ro + colbase + 16 + m];
      }
    }

    const unsigned* srcb = staging + (((t + 1) & 1) << 16) + rowbase * 1024;
    const u64 expect = ((u64)(unsigned)t << 32) | (unsigned)t;

    // ---- cooperative tagged tile load: 4 rounds x 2KB/wave, all in flight ----
    u64 rawv[16];
#pragma unroll
    for (int r = 0; r < 4; ++r) {
      const int ch = chbase + r;
      const unsigned* p = srcb + (ch >> 1) * 1024 + (ch & 1) * 512 + lane * 8;
#pragma unroll
      for (int j = 0; j < 4; ++j)
        rawv[r * 4 + j] = __hip_atomic_load((const u64*)(p + j * 2),
                                            __ATOMIC_RELAXED, __HIP_MEMORY_SCOPE_SYSTEM);
    }

    short* tw = tile2[t & 1];
#pragma unroll
    for (int r = 0; r < 4; ++r) {
      const int ch = chbase + r;
      const unsigned* p = srcb + (ch >> 1) * 1024 + (ch & 1) * 512 + lane * 8;
      // validate round r's tags; the load IS the poll — retry stale rounds
      for (;;) {
        u64 e = 0;
#pragma unroll
        for (int j = 0; j < 4; ++j) e |= (rawv[r * 4 + j] & TAGMASK) ^ expect;
        if (__all(e == 0ull)) break;
        __builtin_amdgcn_s_sleep(1);
#pragma unroll
        for (int j = 0; j < 4; ++j)
          rawv[r * 4 + j] = __hip_atomic_load((const u64*)(p + j * 2),
                                              __ATOMIC_RELAXED, __HIP_MEMORY_SCOPE_SYSTEM);
      }
      // compact value bits -> packed bf16, conflict-free lane-contiguous b128 write
      union { unsigned d[4]; s16x8 s; } pkd;
#pragma unroll
      for (int j = 0; j < 4; ++j) {
        u64 vv = rawv[r * 4 + j];
        pkd.d[j] = (unsigned)((vv >> 16) & 0xFFFFull) | ((unsigned)(vv >> 48) << 16);
      }
      char* dst = (char*)tw + (ch >> 1) * 2048
                + (((ch & 1) * 1024 + lane * 16) ^ ((ch >> 1) << 6));
      *(s16x8*)dst = pkd.s;
    }
    __syncthreads();  // the ONE barrier: tile ready for all 4 waves

    // ---- MFMA over 32 k-chunks from LDS ----
    const char* trd = (const char*)tw + arow * 2048;
    f32x4 cA0 = {0.f,0.f,0.f,0.f}, cA1 = {0.f,0.f,0.f,0.f};
    f32x4 cB0 = {0.f,0.f,0.f,0.f}, cB1 = {0.f,0.f,0.f,0.f};
#pragma unroll
    for (int cc = 0; cc < 32; ++cc) {
      s16x8 a = *(const s16x8*)(trd + ((cc * 64 + q * 16) ^ axor));
      if (cc & 1) {
        cB0 = mfma16(a, bf[cc][0], cB0);
        cB1 = mfma16(a, bf[cc][1], cB1);
      } else {
        cA0 = mfma16(a, bf[cc][0], cA0);
        cA1 = mfma16(a, bf[cc][1], cA1);
      }
    }
    f32x4 s0 = cA0 + cB0;
    f32x4 s1 = cA1 + cB1;

    // tanh + repack through the wave-private LDS buffer (no barrier needed)
    float h0v[4], h1v[4];
    if (q < 2) {
#pragma unroll
      for (int r = 0; r < 4; ++r) {
        h0v[r] = fast_tanh(s0[r] + xp0[r]);
        h1v[r] = fast_tanh(s1[r] + xp1[r]);
        lhv[(lr + r) * 32 + m]      = f2bf(h0v[r]);
        lhv[(lr + r) * 32 + 16 + m] = f2bf(h1v[r]);
      }
    }
    // same-wave LDS write->read: compiler inserts lgkmcnt wait
    long long pk = ((const long long*)lhv)[lane];

    // publish h_t: tagged stores, fire-and-forget (store IS the handoff)
    {
      const unsigned tp1 = (unsigned)(t + 1);
      const u64 pkv = (u64)pk;
      unsigned w0 = ((unsigned)(pkv & 0xFFFFull) << 16) | tp1;
      unsigned w1 = ((unsigned)((pkv >> 16) & 0xFFFFull) << 16) | tp1;
      unsigned w2 = ((unsigned)((pkv >> 32) & 0xFFFFull) << 16) | tp1;
      unsigned w3 = ((unsigned)((pkv >> 48) & 0xFFFFull) << 16) | tp1;
      u64 q0 = (u64)w0 | ((u64)w1 << 32);
      u64 q1 = (u64)w2 | ((u64)w3 << 32);
      unsigned* sp = staging + ((t & 1) << 16) + (rowbase + prow) * 1024
                   + colbase + (lane & 7) * 4;
      __hip_atomic_store((u64*)sp,       q0, __ATOMIC_RELAXED, __HIP_MEMORY_SCOPE_SYSTEM);
      __hip_atomic_store((u64*)(sp + 2), q1, __ATOMIC_RELAXED, __HIP_MEMORY_SCOPE_SYSTEM);
      *(long long*)(hs_bf + (tb + rowbase + prow) * 1024 + colbase + (lane & 7) * 4) = pk;
    }

    // non-protocol fp32 h stores drain whenever (kernel-end flush covers phase C)
    if (q < 2) {
#pragma unroll
      for (int r = 0; r < 4; ++r) {
        int ro = (tb + gr + r) * 1024;
        hid[ro + colbase + m] = h0v[r];
        hid[ro + colbase + 16 + m] = h1v[r];
      }
    }
  }
}

// ---------------- host ----------------

extern "C" void kernel_launch(void* const* d_in, const int* in_sizes, int n_in,
                              void* d_out, int out_size, void* d_ws, size_t ws_size,
                              hipStream_t stream) {
  const float* x  = (const float*)d_in[0];
  const float* h0 = (const float*)d_in[1];
  const float* wI = (const float*)d_in[2];
  const float* wR = (const float*)d_in[3];
  const float* wO = (const float*)d_in[4];
  const float* bR = (const float*)d_in[5];
  const float* bO = (const float*)d_in[6];

  float* outputs = (float*)d_out;                    // [512*64][256]
  float* hid = outputs + 512 * 64 * 256;             // [512*64][1024]

  // workspace layout (~85 MB, unchanged footprint):
  short* x_bf    = (short*)d_ws;                     // 8,388,608 bf16
  short* wI_bf   = x_bf + 8388608;                   // 262,144
  short* wO_bf   = wI_bf + 262144;                   // 262,144
  short* hs_bf   = wO_bf + 262144;                   // 33,554,432
  // staging32 overlays x_bf (512 KB): x_bf is dead after phase A, and
  // init_staging32 runs after phase A (R4-proven ordering).
  unsigned* staging32 = (unsigned*)d_ws;             // [2][64][1024] dwords

  cvt_bf16x4<<<8192, 256, 0, stream>>>(x, x_bf, 2097152);
  cvt_bf16x4<<<256, 256, 0, stream>>>(wI, wI_bf, 65536);
  cvt_bf16x4<<<256, 256, 0, stream>>>(wO, wO_bf, 65536);

  // Phase A: xp = x*wI^T + bR  -> hidden region (in-place seed for recurrence)
  gemm_nt_bias<256><<<dim3(512, 16), 256, 0, stream>>>(x_bf, wI_bf, bR, hid, 1024);
  // staging init AFTER phase A (x_bf consumed; region reused)
  init_staging32<<<512, 256, 0, stream>>>(h0, staging32);
  // Phase B: sequential recurrence (64 WGs x 256 threads)
  rnn_recur<<<64, 256, 0, stream>>>(wR, hid, hs_bf, staging32);
  // Phase C: outputs = h*wO^T + bO
  gemm_nt_bias<1024><<<dim3(512, 4), 256, 0, stream>>>(hs_bf, wO_bf, bO, outputs, 256);
}

// Round 8
// 2046.858 us; speedup vs baseline: 1.1130x; 1.1130x over previous
//
#include <hip/hip_runtime.h>
#include <math.h>

// Problem constants: T=512, B=64, I=256, H=1024, O=256
// d_out layout: outputs [512*64][256] fp32, then hidden_states [512*64][1024] fp32.

typedef __attribute__((ext_vector_type(8))) short s16x8;
typedef __attribute__((ext_vector_type(4))) short s16x4;
typedef __attribute__((ext_vector_type(4))) float f32x4;
typedef unsigned long long u64;

__device__ __forceinline__ short f2bf(float f) {
  union { float f; unsigned u; } v; v.f = f;
  unsigned r = v.u + 0x7FFFu + ((v.u >> 16) & 1u);  // RNE
  return (short)(r >> 16);
}

__device__ __forceinline__ f32x4 mfma16(s16x8 a, s16x8 b, f32x4 c) {
  return __builtin_amdgcn_mfma_f32_16x16x32_bf16(a, b, c, 0, 0, 0);
}

// tanh via v_exp_f32: t = 1 - 2/(e^{2x}+1). Monotone-safe at +-inf, no NaN.
__device__ __forceinline__ float fast_tanh(float x) {
  float e = __expf(2.0f * x);
  return 1.0f - 2.0f * __builtin_amdgcn_rcpf(e + 1.0f);
}

// ---------------- converters / init ----------------

__global__ void cvt_bf16x4(const float* __restrict__ in, short* __restrict__ out, int n4) {
  int i = blockIdx.x * 256 + threadIdx.x;
  if (i < n4) {
    const float4 v = ((const float4*)in)[i];
    s16x4 o = { f2bf(v.x), f2bf(v.y), f2bf(v.z), f2bf(v.w) };
    ((s16x4*)out)[i] = o;
  }
}

// staging32: [2 slots][64 rows][1024] tagged dwords: (bf16 << 16) | step_tag.
// slot1 = h_{-1} = broadcast h0, tag 0 (consumer at t=0 expects tag 0).
// slot0 zeroed: tag 0 never matches its first expected tag (odd t >= 1).
__global__ void init_staging32(const float* __restrict__ h0, unsigned* __restrict__ staging) {
  int i = blockIdx.x * 256 + threadIdx.x;  // 2*64*1024 = 131072
  if (i < 131072) {
    int slot = i >> 16;
    int k = i & 1023;
    staging[i] = slot ? (((unsigned)(unsigned short)f2bf(h0[k])) << 16) : 0u;
  }
}

// ---------------- generic NT GEMM: out[M][N] = A[M][K](bf16) * B[N][K](bf16)^T + bias ----------------

template <int K>
__global__ __launch_bounds__(256) void gemm_nt_bias(
    const short* __restrict__ A, const short* __restrict__ B,
    const float* __restrict__ bias, float* __restrict__ out, int N) {
  const int tid = threadIdx.x;
  const int lane = tid & 63, wv = tid >> 6;
  const int m0 = blockIdx.x * 64 + (wv & 1) * 32;
  const int n0 = blockIdx.y * 64 + (wv >> 1) * 32;
  const int lm = lane & 15, q = lane >> 4;

  const short* a0p = A + (m0 + lm) * K + q * 8;
  const short* a1p = a0p + 16 * K;
  const short* b0p = B + (n0 + lm) * K + q * 8;
  const short* b1p = b0p + 16 * K;

  f32x4 c00 = {0.f,0.f,0.f,0.f}, c01 = {0.f,0.f,0.f,0.f};
  f32x4 c10 = {0.f,0.f,0.f,0.f}, c11 = {0.f,0.f,0.f,0.f};

#pragma unroll
  for (int kk = 0; kk < K; kk += 32) {
    s16x8 a0 = *(const s16x8*)(a0p + kk);
    s16x8 a1 = *(const s16x8*)(a1p + kk);
    s16x8 b0 = *(const s16x8*)(b0p + kk);
    s16x8 b1 = *(const s16x8*)(b1p + kk);
    c00 = mfma16(a0, b0, c00);
    c01 = mfma16(a0, b1, c01);
    c10 = mfma16(a1, b0, c10);
    c11 = mfma16(a1, b1, c11);
  }

  const int col0 = n0 + lm;
  const float bi0 = bias[col0], bi1 = bias[col0 + 16];
#pragma unroll
  for (int r = 0; r < 4; ++r) {
    int row = m0 + q * 4 + r;
    out[row * N + col0]        = c00[r] + bi0;
    out[row * N + col0 + 16]   = c01[r] + bi1;
    out[(row + 16) * N + col0]      = c10[r] + bi0;
    out[(row + 16) * N + col0 + 16] = c11[r] + bi1;
  }
}

// ---------------- recurrent kernel ----------------
// R8 = R7 structure (64 WGs x 256 threads, tag-in-data, double-buffered LDS
// tile, one barrier/step) with the consumer fixed:
//
// R7 BUG (perf): the 4 validation rounds ran SERIALLY — each round's retry
// completed before the next round was validated. First loads at step entry
// are ~always stale (producer stores land later), so every round paid its
// own sequential MALL round-trip: +3 serial RTs, which ate exactly what
// deleting the flag protocol saved (R7 == R6 == 3.65us/step).
//
// R8 consumer: (1) LIGHT PROBE — each lane polls word 0 of each of its 4
// rounds (4x8B, one concurrent bundle) until all tags show t; 4x less
// fabric spam than full reloads, self-paced by the vmcnt wait. Probe is a
// HINT only. (2) FULL concurrent 16-load + concurrent validate-retry as the
// correctness backstop (reload all 16 in ONE flight — never per-round).
// Protocol semantics identical to R7 (single-copy-atomic tagged dwords;
// same slot-reuse induction; same producer fire-and-forget stores).

__global__ __launch_bounds__(256, 1) void rnn_recur(
    const float* __restrict__ wR,     // [1024][1024] fp32, k-major
    float* __restrict__ hid,          // [512*64][1024] fp32: xp on entry, h on exit
    short* __restrict__ hs_bf,        // [512*64][1024] bf16 copy of h (for phase C)
    unsigned* __restrict__ staging)   // [2][64][1024] tagged dwords
{
  __shared__ short tile2[2][8 * 1024];  // 2 x 16KB packed h tiles (8 x 1024 bf16)
  __shared__ short lh[4 * 256];         // per-wave 8x32 repack buffers (4 x 512B)

  const int tid = threadIdx.x;
  const int lane = tid & 63;
  const int v = tid >> 6;             // wave 0..3
  const int g = blockIdx.x & 7;
  const int w = blockIdx.x >> 3;      // 0..7
  const int m = lane & 15, q = lane >> 4;
  const int rowbase = g * 8;
  const int colbase = w * 128 + v * 32;

  // --- one-time: pack wR[:, colbase..colbase+32) into B-fragments in registers ---
  s16x8 bf[32][2];
#pragma unroll
  for (int cc = 0; cc < 32; ++cc) {
#pragma unroll
    for (int tn = 0; tn < 2; ++tn) {
      const int kb = cc * 32 + q * 8;
      const int n = colbase + tn * 16 + m;
      s16x8 vv;
#pragma unroll
      for (int j = 0; j < 8; ++j) vv[j] = f2bf(wR[(kb + j) * 1024 + n]);
      bf[cc][tn] = vv;
    }
  }

  const int gr = rowbase + q * 4;     // epilogue rows (valid when q<2)
  const int lr = q * 4;               // local row base in lh
  const int prow = lane >> 3;         // packed-store row: lane i>>3, 4 cols (i&7)*4
  short* lhv = lh + v * 256;

  // MFMA-read swizzle (verified in R6/R7): byte = arow*2048 + ((cc*64+q*16)^axor)
  const int arow = m & 7;
  const int axor = arow << 6;

  const u64 TAGMASK = 0x0000FFFF0000FFFFull;
  const int chbase = v * 4;           // this wave's 4 load-chunks (of 16)

#pragma unroll 1
  for (int t = 0; t < 512; ++t) {
    const int tb = t * 64;

    // prefetch xp (independent of the protocol) to hide HBM latency
    float xp0[4] = {0.f,0.f,0.f,0.f}, xp1[4] = {0.f,0.f,0.f,0.f};
    if (q < 2) {
#pragma unroll
      for (int r = 0; r < 4; ++r) {
        int ro = (tb + gr + r) * 1024;
        xp0[r] = hid[ro + colbase + m];
        xp1[r] = hid[ro + colbase + 16 + m];
      }
    }

    const unsigned* srcb = staging + (((t + 1) & 1) << 16) + rowbase * 1024;
    const u64 expect = ((u64)(unsigned)t << 32) | (unsigned)t;

    // ---- light probe: word 0 of each round, one concurrent bundle ----
    for (;;) {
      u64 p0 = __hip_atomic_load(
          (const u64*)(srcb + ((chbase + 0) >> 1) * 1024 + ((chbase + 0) & 1) * 512 + lane * 8),
          __ATOMIC_RELAXED, __HIP_MEMORY_SCOPE_SYSTEM);
      u64 p1 = __hip_atomic_load(
          (const u64*)(srcb + ((chbase + 1) >> 1) * 1024 + ((chbase + 1) & 1) * 512 + lane * 8),
          __ATOMIC_RELAXED, __HIP_MEMORY_SCOPE_SYSTEM);
      u64 p2 = __hip_atomic_load(
          (const u64*)(srcb + ((chbase + 2) >> 1) * 1024 + ((chbase + 2) & 1) * 512 + lane * 8),
          __ATOMIC_RELAXED, __HIP_MEMORY_SCOPE_SYSTEM);
      u64 p3 = __hip_atomic_load(
          (const u64*)(srcb + ((chbase + 3) >> 1) * 1024 + ((chbase + 3) & 1) * 512 + lane * 8),
          __ATOMIC_RELAXED, __HIP_MEMORY_SCOPE_SYSTEM);
      u64 e = ((p0 & TAGMASK) ^ expect) | ((p1 & TAGMASK) ^ expect)
            | ((p2 & TAGMASK) ^ expect) | ((p3 & TAGMASK) ^ expect);
      if (__all(e == 0ull)) break;
      // no s_sleep: the 4-load vmcnt wait self-paces the loop at ~1 RT
    }
    asm volatile("" ::: "memory");  // probe is a hint; keep full loads below it

    // ---- full concurrent load + concurrent validate (correctness backstop) ----
    u64 rawv[16];
#pragma unroll
    for (int r = 0; r < 4; ++r) {
      const int ch = chbase + r;
      const unsigned* p = srcb + (ch >> 1) * 1024 + (ch & 1) * 512 + lane * 8;
#pragma unroll
      for (int j = 0; j < 4; ++j)
        rawv[r * 4 + j] = __hip_atomic_load((const u64*)(p + j * 2),
                                            __ATOMIC_RELAXED, __HIP_MEMORY_SCOPE_SYSTEM);
    }
    for (;;) {
      u64 e = 0;
#pragma unroll
      for (int i = 0; i < 16; ++i) e |= (rawv[i] & TAGMASK) ^ expect;
      if (__all(e == 0ull)) break;
      __builtin_amdgcn_s_sleep(1);
#pragma unroll
      for (int r = 0; r < 4; ++r) {
        const int ch = chbase + r;
        const unsigned* p = srcb + (ch >> 1) * 1024 + (ch & 1) * 512 + lane * 8;
#pragma unroll
        for (int j = 0; j < 4; ++j)
          rawv[r * 4 + j] = __hip_atomic_load((const u64*)(p + j * 2),
                                              __ATOMIC_RELAXED, __HIP_MEMORY_SCOPE_SYSTEM);
      }
    }

    // ---- compact value bits -> packed bf16, conflict-free b128 LDS writes ----
    short* tw = tile2[t & 1];
#pragma unroll
    for (int r = 0; r < 4; ++r) {
      const int ch = chbase + r;
      union { unsigned d[4]; s16x8 s; } pkd;
#pragma unroll
      for (int j = 0; j < 4; ++j) {
        u64 vv = rawv[r * 4 + j];
        pkd.d[j] = (unsigned)((vv >> 16) & 0xFFFFull) | ((unsigned)(vv >> 48) << 16);
      }
      char* dst = (char*)tw + (ch >> 1) * 2048
                + (((ch & 1) * 1024 + lane * 16) ^ ((ch >> 1) << 6));
      *(s16x8*)dst = pkd.s;
    }
    __syncthreads();  // the ONE barrier: tile ready for all 4 waves

    // ---- MFMA over 32 k-chunks from LDS ----
    const char* trd = (const char*)tw + arow * 2048;
    f32x4 cA0 = {0.f,0.f,0.f,0.f}, cA1 = {0.f,0.f,0.f,0.f};
    f32x4 cB0 = {0.f,0.f,0.f,0.f}, cB1 = {0.f,0.f,0.f,0.f};
#pragma unroll
    for (int cc = 0; cc < 32; ++cc) {
      s16x8 a = *(const s16x8*)(trd + ((cc * 64 + q * 16) ^ axor));
      if (cc & 1) {
        cB0 = mfma16(a, bf[cc][0], cB0);
        cB1 = mfma16(a, bf[cc][1], cB1);
      } else {
        cA0 = mfma16(a, bf[cc][0], cA0);
        cA1 = mfma16(a, bf[cc][1], cA1);
      }
    }
    f32x4 s0 = cA0 + cB0;
    f32x4 s1 = cA1 + cB1;

    // tanh + repack through the wave-private LDS buffer (no barrier needed)
    float h0v[4], h1v[4];
    if (q < 2) {
#pragma unroll
      for (int r = 0; r < 4; ++r) {
        h0v[r] = fast_tanh(s0[r] + xp0[r]);
        h1v[r] = fast_tanh(s1[r] + xp1[r]);
        lhv[(lr + r) * 32 + m]      = f2bf(h0v[r]);
        lhv[(lr + r) * 32 + 16 + m] = f2bf(h1v[r]);
      }
    }
    // same-wave LDS write->read: compiler inserts lgkmcnt wait
    long long pk = ((const long long*)lhv)[lane];

    // publish h_t: tagged stores, fire-and-forget (store IS the handoff)
    {
      const unsigned tp1 = (unsigned)(t + 1);
      const u64 pkv = (u64)pk;
      unsigned w0 = ((unsigned)(pkv & 0xFFFFull) << 16) | tp1;
      unsigned w1 = ((unsigned)((pkv >> 16) & 0xFFFFull) << 16) | tp1;
      unsigned w2 = ((unsigned)((pkv >> 32) & 0xFFFFull) << 16) | tp1;
      unsigned w3 = ((unsigned)((pkv >> 48) & 0xFFFFull) << 16) | tp1;
      u64 q0 = (u64)w0 | ((u64)w1 << 32);
      u64 q1 = (u64)w2 | ((u64)w3 << 32);
      unsigned* sp = staging + ((t & 1) << 16) + (rowbase + prow) * 1024
                   + colbase + (lane & 7) * 4;
      __hip_atomic_store((u64*)sp,       q0, __ATOMIC_RELAXED, __HIP_MEMORY_SCOPE_SYSTEM);
      __hip_atomic_store((u64*)(sp + 2), q1, __ATOMIC_RELAXED, __HIP_MEMORY_SCOPE_SYSTEM);
      *(long long*)(hs_bf + (tb + rowbase + prow) * 1024 + colbase + (lane & 7) * 4) = pk;
    }

    // non-protocol fp32 h stores drain whenever (kernel-end flush covers phase C)
    if (q < 2) {
#pragma unroll
      for (int r = 0; r < 4; ++r) {
        int ro = (tb + gr + r) * 1024;
        hid[ro + colbase + m] = h0v[r];
        hid[ro + colbase + 16 + m] = h1v[r];
      }
    }
  }
}

// ---------------- host ----------------

extern "C" void kernel_launch(void* const* d_in, const int* in_sizes, int n_in,
                              void* d_out, int out_size, void* d_ws, size_t ws_size,
                              hipStream_t stream) {
  const float* x  = (const float*)d_in[0];
  const float* h0 = (const float*)d_in[1];
  const float* wI = (const float*)d_in[2];
  const float* wR = (const float*)d_in[3];
  const float* wO = (const float*)d_in[4];
  const float* bR = (const float*)d_in[5];
  const float* bO = (const float*)d_in[6];

  float* outputs = (float*)d_out;                    // [512*64][256]
  float* hid = outputs + 512 * 64 * 256;             // [512*64][1024]

  // workspace layout (~85 MB, unchanged footprint):
  short* x_bf    = (short*)d_ws;                     // 8,388,608 bf16
  short* wI_bf   = x_bf + 8388608;                   // 262,144
  short* wO_bf   = wI_bf + 262144;                   // 262,144
  short* hs_bf   = wO_bf + 262144;                   // 33,554,432
  // staging32 overlays x_bf (512 KB): x_bf is dead after phase A, and
  // init_staging32 runs after phase A (R4-proven ordering).
  unsigned* staging32 = (unsigned*)d_ws;             // [2][64][1024] dwords

  cvt_bf16x4<<<8192, 256, 0, stream>>>(x, x_bf, 2097152);
  cvt_bf16x4<<<256, 256, 0, stream>>>(wI, wI_bf, 65536);
  cvt_bf16x4<<<256, 256, 0, stream>>>(wO, wO_bf, 65536);

  // Phase A: xp = x*wI^T + bR  -> hidden region (in-place seed for recurrence)
  gemm_nt_bias<256><<<dim3(512, 16), 256, 0, stream>>>(x_bf, wI_bf, bR, hid, 1024);
  // staging init AFTER phase A (x_bf consumed; region reused)
  init_staging32<<<512, 256, 0, stream>>>(h0, staging32);
  // Phase B: sequential recurrence (64 WGs x 256 threads)
  rnn_recur<<<64, 256, 0, stream>>>(wR, hid, hs_bf, staging32);
  // Phase C: outputs = h*wO^T + bO
  gemm_nt_bias<1024><<<dim3(512, 4), 256, 0, stream>>>(hs_bf, wO_bf, bO, outputs, 256);
}